// Round 6
// baseline (82.515 us; speedup 1.0000x reference)
//
#include <hip/hip_runtime.h>
#include <math.h>

#define TPB 1024
#define NBUK 4096
#define NPL 20                 // LGG pair blocks
#define NPH 74                 // HGG pair blocks
#define NSLOT (2 + NPL + NPH)  // 96: 0,1 Cox; 2..21 LGG; 22..95 HGG
#define FLAG_MAGIC 0x13579BDFu

struct Slot {
  double a, b;        // cox: (sum3,0)/(0,sum1); pair: (totL, totH)
  unsigned int c, d;  // pair: (nL, nH)
  unsigned int flag;  // FLAG_MAGIC when valid (ws poison 0xAA != magic)
  unsigned int pad;
};

__device__ const float RISK[9] = {1.0f, 1.0f, 0.91f, 1.12f, 1.71f,
                                  2.41f, 3.27f, 5.18f, 8.44f};

__device__ __forceinline__ int bucketOf(float s) {
  int b = (int)(s * 4096.0f);  // power-of-two scale: exact, monotone
  return b < 0 ? 0 : (b > 4095 ? 4095 : b);
}
__device__ __forceinline__ int decadeOf(int a) {
  int d = a / 10;
  return d > 8 ? 8 : (d < 0 ? 0 : d);
}
__device__ __forceinline__ double wredsumd(double v) {
  for (int off = 32; off; off >>= 1) v += __shfl_down(v, off, 64);
  return v;
}
__device__ __forceinline__ unsigned int wredsumu(unsigned int v) {
  for (int off = 32; off; off >>= 1) v += __shfl_down(v, off, 64);
  return v;
}

__global__ __launch_bounds__(TPB) void fused_kernel(
    const float* __restrict__ h3, const float* __restrict__ h1,
    const float* __restrict__ st, const float* __restrict__ cen,
    const int* __restrict__ age, const int* __restrict__ grade,
    const float* __restrict__ b1p, const float* __restrict__ b2p,
    const float* __restrict__ vars, Slot* __restrict__ slots,
    float* __restrict__ out, int B) {
  __shared__ int smem_i[18432];  // 72 KB, overlaid per branch
  __shared__ int wsi[16];
  __shared__ float wsA[16];
  __shared__ double dred[32];
  __shared__ unsigned int ured[16];

  const int t = threadIdx.x, lane = t & 63, wid = t >> 6;
  const int bid = blockIdx.x;

  if (bid < 2) {
    // ================= Cox partial-likelihood (one hazard array) ==========
    const float* h = (bid == 0) ? h3 : h1;
    int* cursor = smem_i;                                    // [4096] 16 KB
    unsigned short* ord = (unsigned short*)(smem_i + 4096);  // [4096]  8 KB
    float* bs = (float*)(smem_i + 6144);                     // [4096] 16 KB
    float* h_lds = (float*)(smem_i + 10240);                 // [4096] 16 KB
    float* st_lds = (float*)(smem_i + 14336);                // [4096] 16 KB

    // stage h/st/cen (vectorized) + zero cursor (one pass, one barrier)
    float s4[4], hv4[4], c4[4];
    ((int4*)cursor)[t] = make_int4(0, 0, 0, 0);
    if (4 * t + 3 < B) {
      float4 hv = ((const float4*)h)[t];
      float4 sv = ((const float4*)st)[t];
      float4 cv = ((const float4*)cen)[t];
      ((float4*)h_lds)[t] = hv;
      ((float4*)st_lds)[t] = sv;
      hv4[0] = hv.x; hv4[1] = hv.y; hv4[2] = hv.z; hv4[3] = hv.w;
      s4[0] = sv.x; s4[1] = sv.y; s4[2] = sv.z; s4[3] = sv.w;
      c4[0] = cv.x; c4[1] = cv.y; c4[2] = cv.z; c4[3] = cv.w;
    } else {
      for (int k = 0; k < 4; ++k) {
        int i = 4 * t + k;
        float hh = (i < B) ? h[i] : 0.f;
        float ss = (i < B) ? st[i] : 2.f;  // sentinel > any st
        h_lds[i] = hh;
        st_lds[i] = ss;
        hv4[k] = hh;
        s4[k] = ss;
        c4[k] = (i < B) ? cen[i] : 0.f;
      }
    }
    __syncthreads();
    int myb[4];
    for (int k = 0; k < 4; ++k) {
      int i = 4 * t + k;
      int b = (i < B) ? bucketOf(s4[k]) : -1;
      myb[k] = b;
      if (b >= 0) atomicAdd(&cursor[b], 1);
    }
    __syncthreads();
    // exclusive prefix of bucket counts -> bucket starts
    int c0 = cursor[4 * t], c1 = cursor[4 * t + 1], c2 = cursor[4 * t + 2],
        c3 = cursor[4 * t + 3];
    int loc = c0 + c1 + c2 + c3;
    int v = loc;
    for (int off = 1; off < 64; off <<= 1) {
      int u = __shfl_up(v, off, 64);
      if (lane >= off) v += u;
    }
    if (lane == 63) wsi[wid] = v;
    __syncthreads();
    if (t == 0) {
      int run = 0;
      for (int w = 0; w < 16; ++w) { int x = wsi[w]; wsi[w] = run; run += x; }
    }
    __syncthreads();
    int excl = v - loc + wsi[wid];
    cursor[4 * t + 0] = excl;
    cursor[4 * t + 1] = excl + c0;
    cursor[4 * t + 2] = excl + c0 + c1;
    cursor[4 * t + 3] = excl + c0 + c1 + c2;
    __syncthreads();
    // counting-sort scatter; after this cursor[b] = end of bucket b
    for (int k = 0; k < 4; ++k)
      if (myb[k] >= 0) {
        int slot = atomicAdd(&cursor[myb[k]], 1);
        ord[slot] = (unsigned short)(4 * t + k);
      }
    __syncthreads();
    // per-bucket exp sums (thread owns buckets 4t..4t+3), all LDS
    float pv[4];
    for (int k = 0; k < 4; ++k) {
      int bb = 4 * t + k;
      int lo_ = bb ? cursor[bb - 1] : 0;
      int hi_ = cursor[bb];
      float s = 0.f;
      for (int m = lo_; m < hi_; ++m) s += __expf(h_lds[ord[m]]);
      pv[k] = s;
    }
    // inclusive suffix sum over 4096 buckets
    float l3 = pv[3], l2 = pv[2] + l3, l1 = pv[1] + l2, l0 = pv[0] + l1;
    float vA = l0;
    for (int off = 1; off < 64; off <<= 1) {
      float u = __shfl_down(vA, off, 64);
      if (lane + off < 64) vA += u;
    }
    if (lane == 0) wsA[wid] = vA;
    __syncthreads();
    if (t == 0) {
      float r = 0.f;
      for (int w = 15; w >= 0; --w) { float x = wsA[w]; wsA[w] = r; r += x; }
    }
    __syncthreads();
    float tail = (vA - l0) + wsA[wid];
    bs[4 * t + 0] = l0 + tail;
    bs[4 * t + 1] = l1 + tail;
    bs[4 * t + 2] = l2 + tail;
    bs[4 * t + 3] = l3 + tail;
    __syncthreads();
    // per-element log-risk (exact tie handling within own bucket)
    double a = 0.0;
    for (int k = 0; k < 4; ++k) {
      int i = 4 * t + k;
      if (i >= B) break;
      float ci = c4[k];
      if (ci == 0.f) continue;
      float si = s4[k];
      int b = myb[k];
      float T = (b + 1 < NBUK) ? bs[b + 1] : 0.f;
      int lo_ = b ? cursor[b - 1] : 0;
      int hi_ = cursor[b];
      for (int m = lo_; m < hi_; ++m) {
        int j = ord[m];
        if (st_lds[j] >= si) T += __expf(h_lds[j]);
      }
      a += (double)((hv4[k] - __logf(T)) * ci);
    }
    double w = wredsumd(a);
    if (lane == 0) dred[wid] = w;
    __syncthreads();
    if (t == 0) {
      double S = 0;
      for (int w2 = 0; w2 < 16; ++w2) S += dred[w2];
      slots[bid].a = (bid == 0) ? S : 0.0;
      slots[bid].b = (bid == 0) ? 0.0 : S;
      slots[bid].c = 0u;
      slots[bid].d = 0u;
      __hip_atomic_store(&slots[bid].flag, FLAG_MAGIC, __ATOMIC_RELEASE,
                         __HIP_MEMORY_SCOPE_AGENT);
    }
  } else {
    // ============ pair-rank loss (specialized LGG / HGG blocks) ===========
    const bool isL = (bid < 2 + NPL);
    const int pb = isL ? (bid - 2) : (bid - 2 - NPL);
    const int NP = isL ? NPL : NPH;
    uint2* pool = (uint2*)smem_i;           // [4096] 32 KB packed records
    float* aLUT = (float*)(smem_i + 8192);  // [81] swish alpha LUT
    int* wcY = (int*)(aLUT + 81);           // [16] per-wave young counts
    int* wcO = wcY + 16;                    // [16] per-wave old counts
    const float beta = isL ? b1p[0] : b2p[0];
    const int athr = isL ? 40 : 65;

    if (t < 81) {
      int dy = t / 9, dq = t - 9 * dy;
      float d = (RISK[dq] - RISK[dy]) * 0.125f;
      aLUT[t] = d / (1.f + __expf(-beta * d));  // swish(d, beta)
    }
    // classify (vectorized loads); cat 0 = young, 1 = old, -1 = skip
    int av4[4], cat[4];
    float hv4[4];
    if (4 * t + 3 < B) {
      int4 av = ((const int4*)age)[t];
      int4 gv = ((const int4*)grade)[t];
      float4 hv = ((const float4*)h3)[t];
      av4[0] = av.x; av4[1] = av.y; av4[2] = av.z; av4[3] = av.w;
      hv4[0] = hv.x; hv4[1] = hv.y; hv4[2] = hv.z; hv4[3] = hv.w;
      int gv4[4] = {gv.x, gv.y, gv.z, gv.w};
      for (int k = 0; k < 4; ++k) {
        bool ok = isL ? (gv4[k] == 0) : (gv4[k] == 1 || gv4[k] == 2);
        cat[k] = ok ? (av4[k] < athr ? 0 : 1) : -1;
      }
    } else {
      for (int k = 0; k < 4; ++k) {
        int i = 4 * t + k;
        cat[k] = -1;
        av4[k] = 0;
        hv4[k] = 0.f;
        if (i < B) {
          int g = grade[i];
          av4[k] = age[i];
          hv4[k] = h3[i];
          bool ok = isL ? (g == 0) : (g == 1 || g == 2);
          if (ok) cat[k] = (av4[k] < athr) ? 0 : 1;
        }
      }
    }
    // wave-level histogram via ballot (pool order is irrelevant: the pair
    // sum depends only on membership + stored original index)
    unsigned long long mY[4], mO[4];
    int yc = 0, oc = 0;
    for (int k = 0; k < 4; ++k) {
      mY[k] = __ballot(cat[k] == 0);
      mO[k] = __ballot(cat[k] == 1);
      yc += __popcll(mY[k]);
      oc += __popcll(mO[k]);
    }
    if (lane == 0) { wcY[wid] = yc; wcO[wid] = oc; }
    __syncthreads();
    int ny = 0, no = 0, bY = 0, bO = 0;
    for (int w = 0; w < 16; ++w) {
      int y = wcY[w], o = wcO[w];
      if (w < wid) { bY += y; bO += o; }
      ny += y;
      no += o;
    }
    // scatter: register-computed slots, zero atomics
    const unsigned long long lt = (1ull << lane) - 1ull;
    int offY = 0, offO = 0;
    for (int k = 0; k < 4; ++k) {
      if (cat[k] >= 0) {
        int i = 4 * t + k;
        uint2 rec = make_uint2(__float_as_uint(hv4[k]),
                               (unsigned)((i << 4) | decadeOf(av4[k])));
        int slot = (cat[k] == 0)
                       ? (bY + offY + __popcll(mY[k] & lt))
                       : (ny + bO + offO + __popcll(mO[k] & lt));
        pool[slot] = rec;
      }
      offY += __popcll(mY[k]);
      offO += __popcll(mO[k]);
    }
    __syncthreads();

    double tot = 0.0;
    unsigned int n = 0;
    // youngs strided across blocks, olds strided across threads
    for (int yi = pb; yi < ny; yi += NP) {
      uint2 yr = pool[yi];
      float h3y = __uint_as_float(yr.x);
      int iy = (int)(yr.y >> 4);
      const float* aRow = &aLUT[(yr.y & 15u) * 9];
      for (int oi = t; oi < no; oi += TPB) {
        uint2 orc = pool[ny + oi];
        if ((int)(orc.y >> 4) > iy) {
          float x = aRow[orc.y & 15u] * (h3y - __uint_as_float(orc.x));
          float sp = fmaxf(x, 0.f) + __logf(1.f + __expf(-fabsf(x)));
          tot += (double)sp;
          n++;
        }
      }
    }
    double wt = wredsumd(tot);
    unsigned int un = wredsumu(n);
    if (lane == 0) { dred[wid] = wt; ured[wid] = un; }
    __syncthreads();
    if (t == 0) {
      double S = 0;
      unsigned int N = 0;
      for (int w = 0; w < 16; ++w) { S += dred[w]; N += ured[w]; }
      slots[bid].a = isL ? S : 0.0;
      slots[bid].b = isL ? 0.0 : S;
      slots[bid].c = isL ? N : 0u;
      slots[bid].d = isL ? 0u : N;
      __hip_atomic_store(&slots[bid].flag, FLAG_MAGIC, __ATOMIC_RELEASE,
                         __HIP_MEMORY_SCOPE_AGENT);
    }
  }

  // ==== last block (early-finishing pair block), wave 0: spin + finalize ===
  // All 96 blocks are co-resident (96 << 256 CUs): spin cannot deadlock.
  if (bid == NSLOT - 1 && wid == 0) {
    double s3 = 0, s1 = 0, tl = 0, th = 0;
    unsigned long long nl = 0, nh = 0;
    for (int s = lane; s < NSLOT; s += 64) {
      while (__hip_atomic_load(&slots[s].flag, __ATOMIC_ACQUIRE,
                               __HIP_MEMORY_SCOPE_AGENT) != FLAG_MAGIC)
        __builtin_amdgcn_s_sleep(2);
      double a = slots[s].a;
      double b = slots[s].b;
      unsigned int c = slots[s].c;
      unsigned int d = slots[s].d;
      if (s < 2) {
        s3 += a;
        s1 += b;
      } else {
        tl += a;
        th += b;
        nl += c;
        nh += d;
      }
    }
    for (int off = 32; off; off >>= 1) {
      s3 += __shfl_down(s3, off, 64);
      s1 += __shfl_down(s1, off, 64);
      tl += __shfl_down(tl, off, 64);
      th += __shfl_down(th, off, 64);
      nl += __shfl_down(nl, off, 64);
      nh += __shfl_down(nh, off, 64);
    }
    if (lane == 0) {
      float loss3d = (float)(-s3 / (double)B);
      float loss1d = (float)(-s1 / (double)B);
      float lgg = nl ? (float)(tl / (double)nl) : 0.f;
      float hgg = nh ? (float)(th / (double)nh) : 0.f;
      float losscli = lgg + hgg;
      float v0 = vars[0], v2 = vars[2], v3 = vars[3];
      float r = 0.5f * loss3d / (v0 * v0) + logf(v0);
      r += 0.5f * loss1d / (v2 * v2) + logf(v2);
      r += 0.5f * losscli / (v3 * v3) + logf(v3);
      out[0] = r;
    }
  }
}

extern "C" void kernel_launch(void* const* d_in, const int* in_sizes, int n_in,
                              void* d_out, int out_size, void* d_ws,
                              size_t ws_size, hipStream_t stream) {
  const float* h3 = (const float*)d_in[0];
  const float* h1 = (const float*)d_in[1];
  const float* st = (const float*)d_in[2];
  const float* cen = (const float*)d_in[3];
  const float* vars = (const float*)d_in[4];
  const float* beta1 = (const float*)d_in[5];
  const float* beta2 = (const float*)d_in[6];
  const int* age = (const int*)d_in[7];
  const int* grade = (const int*)d_in[8];
  const int B = in_sizes[0];

  Slot* slots = (Slot*)d_ws;  // every slot written unconditionally: no init
  float* out = (float*)d_out;

  fused_kernel<<<NSLOT, TPB, 0, stream>>>(h3, h1, st, cen, age, grade, beta1,
                                          beta2, vars, slots, out, B);
}